// Round 4
// baseline (483.958 us; speedup 1.0000x reference)
//
#include <hip/hip_runtime.h>

typedef unsigned short u16;
typedef unsigned int   u32;

#define NSAMP  15552
#define GRID_B 486     // 486 blocks * 4 waves * 8 samples = 15552

__device__ __forceinline__ u32 bfr(float f){            // f32 -> bf16 bits, RNE
  u32 u = __float_as_uint(f);
  return (u + 0x7FFFu + ((u >> 16) & 1u)) >> 16;
}
__device__ __forceinline__ float sigm(float v){ return 1.0f / (1.0f + __expf(-v)); }
__device__ __forceinline__ float softp(float v){ return (v > 20.f) ? v : log1pf(__expf(v)); }

// ---------------- Kernel A: W transpose->bf16, comb matrix, zero BN acc ----
__global__ void kA(const float* __restrict__ W, const float* __restrict__ al1,
                   const float* __restrict__ al2, const float* __restrict__ w1,
                   const float* __restrict__ w2, const float* __restrict__ a1b,
                   const float* __restrict__ a2b, u16* __restrict__ wt,
                   float* __restrict__ comb, float* __restrict__ mid){
  int idx = blockIdx.x * 256 + threadIdx.x;      // grid 64 -> 16384 elements
  int k = idx >> 7, n = idx & 127;
  wt[n * 128 + k] = (u16)bfr(W[idx]);            // WT[n][k] = W[k][n]
  if (blockIdx.x == 1) mid[threadIdx.x] = 0.f;   // zero BN accumulators (replay-safe)
  if (blockIdx.x == 0){
    float s1 = softp(w1[0]);
    float s2 = softp(w2[0]);
    for (int p = threadIdx.x; p < 289; p += 256){
      int i = p / 17, j = p - i * 17;
      float mij = s1 * (a1b[i*17+j] + sigm(al1[i*17+j])) + s2 * (a2b[i*17+j] + sigm(al2[i*17+j]));
      float mji = s1 * (a1b[j*17+i] + sigm(al1[j*17+i])) + s2 * (a2b[j*17+i] + sigm(al2[j*17+i]));
      comb[i*20 + j] = 0.5f * (mij + mji);
    }
  }
}

// ---------------- Kernel B: main fused per-sample pipeline (ALL-VALU bisect) ----
struct WaveMem {
  float G[17][20];      // Gram dots -> overwritten by A_hat    1360 B
  float zf[17][132];    // z rows, f32 (reused for BN partials) 8976 B
  float scr[64];        // [0..16] inv-norm, [20..36] gate, [40..56] d
};                      // 10592 B
struct BSmem {
  WaveMem wm[4];        // 42368
  float   combs[340];   // 1360
  u16     wtl[128][136];// 34816  -> total 78544 B (2 blocks/CU)
};
static_assert(sizeof(BSmem) <= 81920, "LDS budget");

__global__ __launch_bounds__(256, 2) void kB(
    const float* __restrict__ x, const float* __restrict__ gw,
    const float* __restrict__ gb, const float* __restrict__ combg,
    const u16* __restrict__ wtg, float* __restrict__ mid,
    float* __restrict__ out){
  __shared__ BSmem sm;
  const int tid = threadIdx.x;
  const int w  = tid >> 6;
  const int l  = tid & 63;
  const int g4 = l >> 4;     // 0..3
  const int lc = l & 15;     // 0..15

  for (int p = tid; p < 340; p += 256) sm.combs[p] = combg[p];
  for (int p = tid; p < 8192; p += 256){           // stage WT (u32 pairs)
    int n = p >> 6, k2 = (p & 63) * 2;
    *(u32*)&sm.wtl[n][k2] = ((const u32*)wtg)[p];
  }
  __syncthreads();   // WT/comb staged

  WaveMem& M = sm.wm[w];
  float* zfp = &M.zf[0][0];
  float2 g2 = *(const float2*)(gw + 2*l);          // gate_w channels 2l, 2l+1
  const float gbv = gb[0];
  float sx = 0.f, sy = 0.f, qx = 0.f, qy = 0.f;    // BN partials (channels 2l, 2l+1)
  const int gwave = blockIdx.x * 4 + w;

  for (int it = 0; it < 8; ++it){
    const int s = gwave * 8 + it;
    const float* xs = x + (size_t)s * 2176;
    float2 xr[17];
    #pragma unroll
    for (int j = 0; j < 17; j++) xr[j] = *(const float2*)(xs + j*128 + 2*l);

    // ---- P1: Gram + norms + gate dots, pure f32 lane-butterfly ----
    #pragma unroll
    for (int i = 0; i < 17; i++){
      float p[17];
      #pragma unroll
      for (int j = i; j < 17; j++)
        p[j-i] = xr[i].x*xr[j].x + xr[i].y*xr[j].y;
      float pg = xr[i].x*g2.x + xr[i].y*g2.y;
      #pragma unroll
      for (int m = 1; m <= 32; m <<= 1){
        #pragma unroll
        for (int j = i; j < 17; j++) p[j-i] += __shfl_xor(p[j-i], m, 64);
        pg += __shfl_xor(pg, m, 64);
      }
      #pragma unroll
      for (int j = i; j < 17; j++){
        if (l == j) M.G[i][j] = p[j-i];
        if (i != j && l == i) M.G[j][i] = p[j-i];
      }
      if (l == i){
        M.scr[i]      = 1.0f / fmaxf(sqrtf(p[0]), 1e-12f);  // p[0] = dot(x_i,x_i)
        M.scr[20 + i] = sigm(pg + gbv);
      }
    }
    __syncthreads();   // (1) G + scr ready

    // ---- P2: A construct + degree ----
    const float iv16 = M.scr[16], gt16 = M.scr[36];
    const float ivj  = M.scr[lc];
    float av00[4], av01[4], dp0[4];
    #pragma unroll
    for (int r = 0; r < 4; r++){
      const int i0 = (g4 << 2) + r;
      const float iv0 = M.scr[i0], gi0 = M.scr[20 + i0];
      float dyn = (i0 == lc) ? 2.0f : fmaxf(M.G[i0][lc] * iv0 * ivj, 0.f);
      av00[r] = gi0 * sm.combs[i0*20 + lc] + (1.f - gi0) * dyn;
      float dyn16 = fmaxf(M.G[i0][16] * iv0 * iv16, 0.f);
      float a16 = gi0 * sm.combs[i0*20 + 16] + (1.f - gi0) * dyn16;
      av01[r] = (lc == 0) ? a16 : 0.f;
      dp0[r] = av00[r] + av01[r];
    }
    // row 16 (identical on every g4 group; depends only on lc)
    float dyn10 = fmaxf(M.G[16][lc] * iv16 * ivj, 0.f);
    float av10 = gt16 * sm.combs[16*20 + lc] + (1.f - gt16) * dyn10;
    float av11 = (lc == 0) ? (gt16 * sm.combs[16*20 + 16] + (1.f - gt16) * 2.0f) : 0.f;
    float dp1 = av10 + av11;
    #pragma unroll
    for (int m = 1; m <= 8; m <<= 1){
      #pragma unroll
      for (int r = 0; r < 4; r++) dp0[r] += __shfl_xor(dp0[r], m, 64);
      dp1 += __shfl_xor(dp1, m, 64);
    }
    float dd0[4];
    #pragma unroll
    for (int r = 0; r < 4; r++) dd0[r] = rsqrtf(dp0[r] + 1e-6f);
    float dd1 = rsqrtf(dp1 + 1e-6f);
    if (lc == 0){
      #pragma unroll
      for (int r = 0; r < 4; r++) M.scr[40 + (g4<<2) + r] = dd0[r];
    }
    if (l == 0) M.scr[40 + 16] = dd1;
    __syncthreads();   // (2) d ready

    // ---- P3: A_hat written in place over G ----
    const float dj0 = M.scr[40 + lc];
    const float dj1 = M.scr[40 + 16];
    #pragma unroll
    for (int r = 0; r < 4; r++){
      const int i0 = (g4 << 2) + r;
      M.G[i0][lc] = dd0[r] * av00[r] * dj0;
      if (lc == 0) M.G[i0][16] = dd0[r] * av01[r] * dj1;
    }
    if (g4 == 0) M.G[16][lc] = dd1 * av10 * dj0;
    if (l == 0)  M.G[16][16] = dd1 * av11 * dj1;
    __syncthreads();   // (3) A_hat ready

    // ---- P4: z = A_hat @ x (f32, x in regs; broadcast LDS reads) ----
    for (int i = 0; i < 17; i++){
      const float4 a0 = *(const float4*)&M.G[i][0];
      const float4 a1 = *(const float4*)&M.G[i][4];
      const float4 a2 = *(const float4*)&M.G[i][8];
      const float4 a3 = *(const float4*)&M.G[i][12];
      const float a16 = M.G[i][16];
      float zx = a0.x*xr[0].x,  zy = a0.x*xr[0].y;
      zx += a0.y*xr[1].x;  zy += a0.y*xr[1].y;
      zx += a0.z*xr[2].x;  zy += a0.z*xr[2].y;
      zx += a0.w*xr[3].x;  zy += a0.w*xr[3].y;
      zx += a1.x*xr[4].x;  zy += a1.x*xr[4].y;
      zx += a1.y*xr[5].x;  zy += a1.y*xr[5].y;
      zx += a1.z*xr[6].x;  zy += a1.z*xr[6].y;
      zx += a1.w*xr[7].x;  zy += a1.w*xr[7].y;
      zx += a2.x*xr[8].x;  zy += a2.x*xr[8].y;
      zx += a2.y*xr[9].x;  zy += a2.y*xr[9].y;
      zx += a2.z*xr[10].x; zy += a2.z*xr[10].y;
      zx += a2.w*xr[11].x; zy += a2.w*xr[11].y;
      zx += a3.x*xr[12].x; zy += a3.x*xr[12].y;
      zx += a3.y*xr[13].x; zy += a3.y*xr[13].y;
      zx += a3.z*xr[14].x; zy += a3.z*xr[14].y;
      zx += a3.w*xr[15].x; zy += a3.w*xr[15].y;
      zx += a16*xr[16].x;  zy += a16*xr[16].y;
      float2 zv; zv.x = zx; zv.y = zy;
      *(float2*)&zfp[i*132 + 2*l] = zv;
    }
    __syncthreads();   // (4) z ready

    // ---- P5: h = z @ W, pure VALU (z broadcast from LDS, W^T bf16 2 cols/lane) ----
    float2 hacc[17];
    #pragma unroll
    for (int i = 0; i < 17; i++){ hacc[i].x = 0.f; hacc[i].y = 0.f; }
    const u16* wr0 = &sm.wtl[2*l][0];
    const u16* wr1 = &sm.wtl[2*l + 1][0];
    #pragma unroll 4
    for (int q = 0; q < 32; q++){
      u32 a0 = *(const u32*)&wr0[4*q];
      u32 a1 = *(const u32*)&wr0[4*q + 2];
      u32 b0 = *(const u32*)&wr1[4*q];
      u32 b1 = *(const u32*)&wr1[4*q + 2];
      float wA0 = __uint_as_float(a0 << 16), wA1 = __uint_as_float(a0 & 0xFFFF0000u);
      float wA2 = __uint_as_float(a1 << 16), wA3 = __uint_as_float(a1 & 0xFFFF0000u);
      float wB0 = __uint_as_float(b0 << 16), wB1 = __uint_as_float(b0 & 0xFFFF0000u);
      float wB2 = __uint_as_float(b1 << 16), wB3 = __uint_as_float(b1 & 0xFFFF0000u);
      #pragma unroll
      for (int i = 0; i < 17; i++){
        float4 zq = *(const float4*)&zfp[i*132 + 4*q];
        hacc[i].x += zq.x*wA0 + zq.y*wA1 + zq.z*wA2 + zq.w*wA3;
        hacc[i].y += zq.x*wB0 + zq.y*wB1 + zq.z*wB2 + zq.w*wB3;
      }
    }
    float* ob = out + (size_t)s * 2176;
    #pragma unroll
    for (int i = 0; i < 17; i++){
      *(float2*)&ob[i*128 + 2*l] = hacc[i];
      sx += hacc[i].x; qx += hacc[i].x*hacc[i].x;
      sy += hacc[i].y; qy += hacc[i].y*hacc[i].y;
    }
    // next-iter G/scr writes are separated from this iter's reads by (1)-(4)
  }

  // ---- BN partials: lane owns channels 2l,2l+1; stash in own zf; block-reduce ----
  zfp[2*l]       = sx;  zfp[2*l + 1]       = sy;
  zfp[128 + 2*l] = qx;  zfp[128 + 2*l + 1] = qy;
  __syncthreads();
  float t0 = ((float*)&sm.wm[0].zf[0][0])[tid];
  float t1 = ((float*)&sm.wm[1].zf[0][0])[tid];
  float t2 = ((float*)&sm.wm[2].zf[0][0])[tid];
  float t3 = ((float*)&sm.wm[3].zf[0][0])[tid];
  atomicAdd(&mid[tid], t0 + t1 + t2 + t3);
}

// ---------------- Kernel D: BN + ReLU + residual (in place) ----------------
__global__ __launch_bounds__(256) void kD(const float* __restrict__ x,
    const float* __restrict__ mid, const float* __restrict__ gamma,
    const float* __restrict__ beta, float* __restrict__ out){
  __shared__ float sc[128], sh[128];
  const int t = threadIdx.x;
  if (t < 128){
    const float ic = 1.0f / 264384.0f;     // N*J
    float mean = mid[t] * ic;
    float var  = fmaxf(mid[128 + t] * ic - mean*mean, 0.f);
    float scl  = gamma[t] * rsqrtf(var + 1e-5f);
    sc[t] = scl;
    sh[t] = beta[t] - mean * scl;
  }
  __syncthreads();
  const int total = 8460288;               // 33,841,152 / 4
  for (int i = blockIdx.x*256 + t; i < total; i += 2048*256){
    float4 h  = ((const float4*)out)[i];
    float4 xv = ((const float4*)x)[i];
    int c0 = (i & 31) << 2;
    float4 r;
    r.x = fmaxf(h.x*sc[c0+0] + sh[c0+0], 0.f) + xv.x;
    r.y = fmaxf(h.y*sc[c0+1] + sh[c0+1], 0.f) + xv.y;
    r.z = fmaxf(h.z*sc[c0+2] + sh[c0+2], 0.f) + xv.z;
    r.w = fmaxf(h.w*sc[c0+3] + sh[c0+3], 0.f) + xv.w;
    ((float4*)out)[i] = r;
  }
}

extern "C" void kernel_launch(void* const* d_in, const int* in_sizes, int n_in,
                              void* d_out, int out_size, void* d_ws, size_t ws_size,
                              hipStream_t stream){
  (void)in_sizes; (void)n_in; (void)out_size; (void)ws_size;
  const float* x     = (const float*)d_in[0];
  const float* W     = (const float*)d_in[1];
  // d_in[2] = b : cancelled exactly by training-mode BatchNorm (mean shift)
  const float* al1   = (const float*)d_in[3];
  const float* al2   = (const float*)d_in[4];
  const float* w1    = (const float*)d_in[5];
  const float* w2    = (const float*)d_in[6];
  const float* gw    = (const float*)d_in[7];
  const float* gb    = (const float*)d_in[8];
  const float* gamma = (const float*)d_in[9];
  const float* beta  = (const float*)d_in[10];
  const float* a1b   = (const float*)d_in[11];
  const float* a2b   = (const float*)d_in[12];
  float* out = (float*)d_out;

  float* wsf  = (float*)d_ws;              // ws usage: ~35 KB total
  float* comb = wsf;                       // 384 f32 (17x20 padded)
  u16*   wt   = (u16*)(wsf + 384);         // 16384 bf16
  float* mid  = wsf + 384 + 8192;          // 256 f32 BN accumulators

  hipLaunchKernelGGL(kA, dim3(64),     dim3(256), 0, stream, W, al1, al2, w1, w2, a1b, a2b, wt, comb, mid);
  hipLaunchKernelGGL(kB, dim3(GRID_B), dim3(256), 0, stream, x, gw, gb, comb, wt, mid, out);
  hipLaunchKernelGGL(kD, dim3(2048),   dim3(256), 0, stream, x, mid, gamma, beta, out);
}